// Round 5
// baseline (345.017 us; speedup 1.0000x reference)
//
#include <hip/hip_runtime.h>
#include <hip/hip_bf16.h>
#include <stdint.h>

#define DEV_INLINE __device__ __forceinline__

typedef __attribute__((ext_vector_type(4))) float f32x4;
typedef __attribute__((ext_vector_type(16))) float f32x16;
typedef __attribute__((ext_vector_type(8))) short short8;

static constexpr int S_LEN = 2048;
static constexpr int DM = 1024;
static constexpr int NH = 16;
static constexpr int DK = 64;
static constexpr int BATCH = 4;
static constexpr int M_TOT = BATCH * S_LEN;  // 8192

// Q pre-scale: (1/sqrt(64)) * log2(e) so softmax runs in exp2 domain.
#define QSCALE 0.18033688011112042f

DEV_INLINE unsigned short bf_round(float x) {
  unsigned u = __builtin_bit_cast(unsigned, x);
  u += 0x7fffu + ((u >> 16) & 1u);
  return (unsigned short)(u >> 16);
}

// ---------------- fp32 -> bf16 convert, all 5 tensors in one dispatch ----------------
struct CvtArgs {
  const float* in[5];
  unsigned short* out[5];
};
__global__ __launch_bounds__(256) void cvt_all(CvtArgs a) {
  int bid = blockIdx.x;
  int which, base;
  if (bid < 4096) { which = 0; base = bid; }
  else { int r = bid - 4096; which = 1 + (r >> 9); base = r & 511; }
  const float* __restrict__ in = a.in[which];
  unsigned short* __restrict__ out = a.out[which];
  long i = ((long)base * 256 + threadIdx.x) * 8;
  float4 va = *reinterpret_cast<const float4*>(in + i);
  float4 vb = *reinterpret_cast<const float4*>(in + i + 4);
  union { unsigned short u[8]; uint4 v; } pk;
  pk.u[0] = bf_round(va.x); pk.u[1] = bf_round(va.y);
  pk.u[2] = bf_round(va.z); pk.u[3] = bf_round(va.w);
  pk.u[4] = bf_round(vb.x); pk.u[5] = bf_round(vb.y);
  pk.u[6] = bf_round(vb.z); pk.u[7] = bf_round(vb.w);
  *reinterpret_cast<uint4*>(out + i) = pk.v;
}

// ---------------- async global->LDS 16B ----------------
DEV_INLINE void gload_lds16(const unsigned short* g, unsigned short* l) {
  __builtin_amdgcn_global_load_lds(
      (const __attribute__((address_space(1))) unsigned int*)g,
      (__attribute__((address_space(3))) unsigned int*)l,
      16, 0, 0);
}

// ---------------- fused QKV GEMM ----------------
// C[m][n] = sum_k A[m,k] * W[n,k] + bias[n]; blockIdx.z selects {Q,K,V}.
struct QkvArgs {
  const unsigned short* W[3];
  const float* bias[3];
  unsigned short* out[3];
};
__global__ __launch_bounds__(256) void gemm_qkv(const unsigned short* __restrict__ A,
                                                QkvArgs args) {
  constexpr int K = DM;
  __shared__ unsigned short lA[128 * 32];
  __shared__ unsigned short lB[128 * 32];
  const int tid = threadIdx.x;
  const int wave = tid >> 6, lane = tid & 63;
  const int wm = wave >> 1, wn = wave & 1;
  const int g = lane >> 4, c = lane & 15;
  const int bm = blockIdx.x, bn = blockIdx.y, z = blockIdx.z;

  const unsigned short* __restrict__ W = args.W[z];
  const float* __restrict__ bias = args.bias[z];
  unsigned short* __restrict__ outp = args.out[z];

  const int srow = lane >> 2;
  const int scol = (lane & 3) * 8;

  f32x4 acc[4][4] = {};

  const unsigned short* Abase = A + (long)(bm * 128) * K;
  const unsigned short* Wbase = W + (long)(bn * 128) * K;

  for (int k0 = 0; k0 < K; k0 += 32) {
    __syncthreads();
#pragma unroll
    for (int i = 0; i < 2; ++i) {
      const int row = i * 64 + wave * 16;
      gload_lds16(Abase + (long)(row + srow) * K + k0 + scol, lA + row * 32);
      gload_lds16(Wbase + (long)(row + srow) * K + k0 + scol, lB + row * 32);
    }
    __syncthreads();

    short8 af[4], bf[4];
#pragma unroll
    for (int mi = 0; mi < 4; ++mi)
      af[mi] = *reinterpret_cast<const short8*>(&lA[(wm * 64 + mi * 16 + c) * 32 + g * 8]);
#pragma unroll
    for (int ni = 0; ni < 4; ++ni)
      bf[ni] = *reinterpret_cast<const short8*>(&lB[(wn * 64 + ni * 16 + c) * 32 + g * 8]);
#pragma unroll
    for (int mi = 0; mi < 4; ++mi)
#pragma unroll
      for (int ni = 0; ni < 4; ++ni)
        acc[mi][ni] =
            __builtin_amdgcn_mfma_f32_16x16x32_bf16(af[mi], bf[ni], acc[mi][ni], 0, 0, 0);
  }

#pragma unroll
  for (int mi = 0; mi < 4; ++mi) {
#pragma unroll
    for (int ni = 0; ni < 4; ++ni) {
      const int mg0 = bm * 128 + wm * 64 + mi * 16 + g * 4;
      const int ng = bn * 128 + wn * 64 + ni * 16 + c;
      const float bv = bias[ng];
#pragma unroll
      for (int r = 0; r < 4; ++r) {
        const int m = mg0 + r;
        float v = acc[mi][ni][r] + bv;
        if (z == 0) v *= QSCALE;
        const int b_ = m >> 11, s_ = m & 2047, h_ = ng >> 6, d_ = ng & 63;
        if (z < 2) {
          outp[((long)(b_ * NH + h_) * S_LEN + s_) * DK + d_] = bf_round(v);
        } else {
          outp[((long)(b_ * NH + h_) * DK + d_) * S_LEN + s_] = bf_round(v);
        }
      }
    }
  }
}

// ---------------- output-projection GEMM (fp32 out) ----------------
__global__ __launch_bounds__(256) void gemm_out(const unsigned short* __restrict__ A,
                                                const unsigned short* __restrict__ W,
                                                const float* __restrict__ bias,
                                                float* __restrict__ outp) {
  constexpr int K = DM, N = DM;
  __shared__ unsigned short lA[128 * 32];
  __shared__ unsigned short lB[128 * 32];
  const int tid = threadIdx.x;
  const int wave = tid >> 6, lane = tid & 63;
  const int wm = wave >> 1, wn = wave & 1;
  const int g = lane >> 4, c = lane & 15;
  const int bm = blockIdx.x, bn = blockIdx.y;

  const int srow = lane >> 2;
  const int scol = (lane & 3) * 8;

  f32x4 acc[4][4] = {};

  const unsigned short* Abase = A + (long)(bm * 128) * K;
  const unsigned short* Wbase = W + (long)(bn * 128) * K;

  for (int k0 = 0; k0 < K; k0 += 32) {
    __syncthreads();
#pragma unroll
    for (int i = 0; i < 2; ++i) {
      const int row = i * 64 + wave * 16;
      gload_lds16(Abase + (long)(row + srow) * K + k0 + scol, lA + row * 32);
      gload_lds16(Wbase + (long)(row + srow) * K + k0 + scol, lB + row * 32);
    }
    __syncthreads();

    short8 af[4], bf[4];
#pragma unroll
    for (int mi = 0; mi < 4; ++mi)
      af[mi] = *reinterpret_cast<const short8*>(&lA[(wm * 64 + mi * 16 + c) * 32 + g * 8]);
#pragma unroll
    for (int ni = 0; ni < 4; ++ni)
      bf[ni] = *reinterpret_cast<const short8*>(&lB[(wn * 64 + ni * 16 + c) * 32 + g * 8]);
#pragma unroll
    for (int mi = 0; mi < 4; ++mi)
#pragma unroll
      for (int ni = 0; ni < 4; ++ni)
        acc[mi][ni] =
            __builtin_amdgcn_mfma_f32_16x16x32_bf16(af[mi], bf[ni], acc[mi][ni], 0, 0, 0);
  }

#pragma unroll
  for (int mi = 0; mi < 4; ++mi) {
#pragma unroll
    for (int ni = 0; ni < 4; ++ni) {
      const int mg0 = bm * 128 + wm * 64 + mi * 16 + g * 4;
      const int ng = bn * 128 + wn * 64 + ni * 16 + c;
      const float bv = bias[ng];
#pragma unroll
      for (int r = 0; r < 4; ++r)
        outp[(long)(mg0 + r) * N + ng] = acc[mi][ni][r] + bv;
    }
  }
}

// ---------------- Flash attention, 32x32 MFMA, split-KV x2 + swizzle ----------------
// Q: [BH][S][DK] bf16 (pre-scaled QSCALE), K: [BH][S][DK] bf16, Vt: [BH][DK][S] bf16
// ctx out: [B][S][H*DK] bf16.
// Block = 4 waves = 2 q-tiles x 2 kv-halves; wave owns 32 q-rows x 1024 kv (32 iters).
// Grid 2048 -> 8192 waves (32/CU capacity). No K-prefetch: TLP hides latency, VGPR<=64.
// Partial (m,l,acc) merged across kv-halves via one LDS exchange.
// XCD-chunked swizzle: each XCD gets 256 contiguous blocks = 8 whole heads.
__global__ __launch_bounds__(256) void attn_kernel(const unsigned short* __restrict__ Q,
                                                   const unsigned short* __restrict__ Kb,
                                                   const unsigned short* __restrict__ Vt,
                                                   unsigned short* __restrict__ ctx) {
  __shared__ float xlds[2][64][34];  // [qt][lane][cacc0(16) cacc1(16) m l]
  const int tid = threadIdx.x, wave = tid >> 6, lane = tid & 63;
  const int q = lane & 31;   // q column; also K/V row selector
  const int h = lane >> 5;   // half-wave: owns k-slice h*8..h*8+7 of frags
  const int bid = blockIdx.x;
  const int swz = (bid & 7) * 256 + (bid >> 3);  // nwg=2048, bijective
  const int hd = swz >> 5, qb = swz & 31;
  const int qt = wave & 1, kvh = wave >> 1;
  const int q0 = qb * 64 + qt * 32;

  const unsigned short* Qh = Q + (long)hd * S_LEN * DK;
  const unsigned short* Kh = Kb + (long)hd * S_LEN * DK;
  const unsigned short* Vh = Vt + (long)hd * DK * S_LEN;

  const unsigned short* Kq = Kh + (long)q * DK + h * 8;           // + kv*DK + d0*16
  const unsigned short* Vq0 = Vh + (long)q * S_LEN + h * 8;       // d rows 0..31
  const unsigned short* Vq1 = Vh + (long)(32 + q) * S_LEN + h * 8;

  short8 qf[4];
#pragma unroll
  for (int d0 = 0; d0 < 4; ++d0)
    qf[d0] = *reinterpret_cast<const short8*>(&Qh[(long)(q0 + q) * DK + d0 * 16 + h * 8]);

  f32x16 cacc0 = {}, cacc1 = {};  // ctx^T: d-blocks [0..31], [32..63] x 32 q
  float mrun = -1e30f, lrun = 0.0f;

  const int kvB = kvh * (S_LEN / 2), kvE = kvB + S_LEN / 2;
  for (int kv0 = kvB; kv0 < kvE; kv0 += 32) {
    // ---- K frags for this tile (no prefetch: TLP covers it) ----
    short8 kf[4];
#pragma unroll
    for (int d0 = 0; d0 < 4; ++d0)
      kf[d0] = *reinterpret_cast<const short8*>(Kq + (long)kv0 * DK + d0 * 16);
    // ---- V frags issued early: latency hides under QK^T + softmax ----
    short8 vf[4];
    vf[0] = *reinterpret_cast<const short8*>(Vq0 + kv0);
    vf[1] = *reinterpret_cast<const short8*>(Vq1 + kv0);
    vf[2] = *reinterpret_cast<const short8*>(Vq0 + kv0 + 16);
    vf[3] = *reinterpret_cast<const short8*>(Vq1 + kv0 + 16);

    // ---- QK^T: S^T[32 kv][32 q] (exp2 domain) ----
    f32x16 st = {};
#pragma unroll
    for (int d0 = 0; d0 < 4; ++d0)
      st = __builtin_amdgcn_mfma_f32_32x32x16_bf16(kf[d0], qf[d0], st, 0, 0, 0);
    // lane reg r: q col = q, kv = kv0 + (r&3) + 8*(r>>2) + 4*h

    // ---- online softmax (defer-max, THR=8 in log2 units) ----
    float t8[8];
#pragma unroll
    for (int r = 0; r < 8; ++r) t8[r] = fmaxf(st[r], st[r + 8]);
#pragma unroll
    for (int r = 0; r < 4; ++r) t8[r] = fmaxf(t8[r], t8[r + 4]);
    float pm = fmaxf(fmaxf(t8[0], t8[1]), fmaxf(t8[2], t8[3]));
    pm = fmaxf(pm, __shfl_xor(pm, 32));

    if (__any(pm > mrun + 8.0f)) {  // wave-uniform rescale branch
      const float mnew = fmaxf(mrun, pm);
      const float alpha = __builtin_amdgcn_exp2f(mrun - mnew);
      cacc0 *= alpha;
      cacc1 *= alpha;
      lrun *= alpha;
      mrun = mnew;
    }

    float p[16];
#pragma unroll
    for (int r = 0; r < 16; ++r) p[r] = __builtin_amdgcn_exp2f(st[r] - mrun);
    float s8[8];
#pragma unroll
    for (int r = 0; r < 8; ++r) s8[r] = p[r] + p[r + 8];
#pragma unroll
    for (int r = 0; r < 4; ++r) s8[r] = s8[r] + s8[r + 4];
    float ls = (s8[0] + s8[1]) + (s8[2] + s8[3]);
    ls += __shfl_xor(ls, 32);
    lrun += ls;

    // ---- pack P -> bf16 pairs ----
    unsigned pkA[4], pkB[4];
#pragma unroll
    for (int rq = 0; rq < 4; ++rq) {
      asm("v_cvt_pk_bf16_f32 %0, %1, %2" : "=v"(pkA[rq]) : "v"(p[4 * rq]), "v"(p[4 * rq + 1]));
      asm("v_cvt_pk_bf16_f32 %0, %1, %2" : "=v"(pkB[rq]) : "v"(p[4 * rq + 2]), "v"(p[4 * rq + 3]));
    }

    // ---- PV: ctx^T += V^T[d][kv] @ P^T[kv][q], two 16-kv steps ----
#pragma unroll
    for (int t = 0; t < 2; ++t) {
      unsigned sA = h ? pkA[2 * t] : pkA[2 * t + 1];
      unsigned sB = h ? pkB[2 * t] : pkB[2 * t + 1];
      unsigned rA = (unsigned)__shfl_xor((int)sA, 32);
      unsigned rB = (unsigned)__shfl_xor((int)sB, 32);
      union { unsigned w[4]; short8 v; } pf;
      pf.w[0] = h ? rA : pkA[2 * t];
      pf.w[1] = h ? rB : pkB[2 * t];
      pf.w[2] = h ? pkA[2 * t + 1] : rA;
      pf.w[3] = h ? pkB[2 * t + 1] : rB;
      cacc0 = __builtin_amdgcn_mfma_f32_32x32x16_bf16(vf[2 * t], pf.v, cacc0, 0, 0, 0);
      cacc1 = __builtin_amdgcn_mfma_f32_32x32x16_bf16(vf[2 * t + 1], pf.v, cacc1, 0, 0, 0);
    }
  }

  // ---- merge the two kv-halves (wave kvh=1 -> wave kvh=0) ----
  if (kvh) {
#pragma unroll
    for (int r = 0; r < 16; ++r) {
      xlds[qt][lane][r] = cacc0[r];
      xlds[qt][lane][16 + r] = cacc1[r];
    }
    xlds[qt][lane][32] = mrun;
    xlds[qt][lane][33] = lrun;
  }
  __syncthreads();
  if (kvh) return;

  const float m1 = xlds[qt][lane][32], l1 = xlds[qt][lane][33];
  const float mt = fmaxf(mrun, m1);
  float a0 = __builtin_amdgcn_exp2f(mrun - mt);
  float a1 = __builtin_amdgcn_exp2f(m1 - mt);
  const float inv = 1.0f / (lrun * a0 + l1 * a1);
  a0 *= inv;
  a1 *= inv;

  // ---- epilogue: ctx^T[d][q] -> ctx[b][s=q0+q][h_*64 + d], d = db*32 + 8*rq + 4*h + rr ----
  const int b_ = hd >> 4, h_ = hd & 15;
  const long row = ((long)b_ * S_LEN + q0 + q) * DM + h_ * DK;
#pragma unroll
  for (int rq = 0; rq < 4; ++rq) {
    ushort4 w0, w1;
    w0.x = bf_round(cacc0[4 * rq + 0] * a0 + xlds[qt][lane][4 * rq + 0] * a1);
    w0.y = bf_round(cacc0[4 * rq + 1] * a0 + xlds[qt][lane][4 * rq + 1] * a1);
    w0.z = bf_round(cacc0[4 * rq + 2] * a0 + xlds[qt][lane][4 * rq + 2] * a1);
    w0.w = bf_round(cacc0[4 * rq + 3] * a0 + xlds[qt][lane][4 * rq + 3] * a1);
    w1.x = bf_round(cacc1[4 * rq + 0] * a0 + xlds[qt][lane][16 + 4 * rq + 0] * a1);
    w1.y = bf_round(cacc1[4 * rq + 1] * a0 + xlds[qt][lane][16 + 4 * rq + 1] * a1);
    w1.z = bf_round(cacc1[4 * rq + 2] * a0 + xlds[qt][lane][16 + 4 * rq + 2] * a1);
    w1.w = bf_round(cacc1[4 * rq + 3] * a0 + xlds[qt][lane][16 + 4 * rq + 3] * a1);
    *reinterpret_cast<ushort4*>(&ctx[row + 8 * rq + 4 * h]) = w0;
    *reinterpret_cast<ushort4*>(&ctx[row + 32 + 8 * rq + 4 * h]) = w1;
  }
}

extern "C" void kernel_launch(void* const* d_in, const int* in_sizes, int n_in,
                              void* d_out, int out_size, void* d_ws, size_t ws_size,
                              hipStream_t stream) {
  const float* X  = (const float*)d_in[0];
  const float* Wq = (const float*)d_in[1];
  const float* bq = (const float*)d_in[2];
  const float* Wk = (const float*)d_in[3];
  const float* bk = (const float*)d_in[4];
  const float* Wv = (const float*)d_in[5];
  const float* bv = (const float*)d_in[6];
  const float* Wo = (const float*)d_in[7];
  const float* bo = (const float*)d_in[8];

  char* ws = (char*)d_ws;
  const long MB = 1l << 20;
  unsigned short* Xbf = (unsigned short*)(ws + 0 * MB);   // 16 MB
  unsigned short* Ctx = Xbf;                              // alias: X dead after V GEMM
  unsigned short* Wqb = (unsigned short*)(ws + 16 * MB);  // 2 MB each
  unsigned short* Wkb = (unsigned short*)(ws + 18 * MB);
  unsigned short* Wvb = (unsigned short*)(ws + 20 * MB);
  unsigned short* Wob = (unsigned short*)(ws + 22 * MB);
  unsigned short* Qb  = (unsigned short*)(ws + 24 * MB);  // 16 MB
  unsigned short* Kbf = (unsigned short*)(ws + 40 * MB);  // 16 MB
  unsigned short* Vtb = (unsigned short*)(ws + 56 * MB);  // 16 MB, ends at 72 MB

  CvtArgs ca;
  ca.in[0] = X;  ca.out[0] = Xbf;
  ca.in[1] = Wq; ca.out[1] = Wqb;
  ca.in[2] = Wk; ca.out[2] = Wkb;
  ca.in[3] = Wv; ca.out[3] = Wvb;
  ca.in[4] = Wo; ca.out[4] = Wob;
  cvt_all<<<4096 + 4 * 512, 256, 0, stream>>>(ca);

  QkvArgs qa;
  qa.W[0] = Wqb; qa.bias[0] = bq; qa.out[0] = Qb;
  qa.W[1] = Wkb; qa.bias[1] = bk; qa.out[1] = Kbf;
  qa.W[2] = Wvb; qa.bias[2] = bv; qa.out[2] = Vtb;
  gemm_qkv<<<dim3(M_TOT / 128, DM / 128, 3), 256, 0, stream>>>(Xbf, qa);

  attn_kernel<<<dim3(2048), 256, 0, stream>>>(Qb, Kbf, Vtb, Ctx);

  gemm_out<<<dim3(M_TOT / 128, DM / 128), 256, 0, stream>>>(Ctx, Wob, bo, (float*)d_out);
}

// Round 6
// 231.814 us; speedup vs baseline: 1.4883x; 1.4883x over previous
//
#include <hip/hip_runtime.h>
#include <hip/hip_bf16.h>
#include <stdint.h>

#define DEV_INLINE __device__ __forceinline__

typedef __attribute__((ext_vector_type(4))) float f32x4;
typedef __attribute__((ext_vector_type(16))) float f32x16;
typedef __attribute__((ext_vector_type(8))) short short8;

static constexpr int S_LEN = 2048;
static constexpr int DM = 1024;
static constexpr int NH = 16;
static constexpr int DK = 64;
static constexpr int BATCH = 4;
static constexpr int M_TOT = BATCH * S_LEN;  // 8192

// Q pre-scale: (1/sqrt(64)) * log2(e) so softmax runs in exp2 domain.
#define QSCALE 0.18033688011112042f

DEV_INLINE unsigned short bf_round(float x) {
  unsigned u = __builtin_bit_cast(unsigned, x);
  u += 0x7fffu + ((u >> 16) & 1u);
  return (unsigned short)(u >> 16);
}

// ---------------- fp32 -> bf16 convert, all 5 tensors in one dispatch ----------------
struct CvtArgs {
  const float* in[5];
  unsigned short* out[5];
};
__global__ __launch_bounds__(256) void cvt_all(CvtArgs a) {
  int bid = blockIdx.x;
  int which, base;
  if (bid < 4096) { which = 0; base = bid; }
  else { int r = bid - 4096; which = 1 + (r >> 9); base = r & 511; }
  const float* __restrict__ in = a.in[which];
  unsigned short* __restrict__ out = a.out[which];
  long i = ((long)base * 256 + threadIdx.x) * 8;
  float4 va = *reinterpret_cast<const float4*>(in + i);
  float4 vb = *reinterpret_cast<const float4*>(in + i + 4);
  union { unsigned short u[8]; uint4 v; } pk;
  pk.u[0] = bf_round(va.x); pk.u[1] = bf_round(va.y);
  pk.u[2] = bf_round(va.z); pk.u[3] = bf_round(va.w);
  pk.u[4] = bf_round(vb.x); pk.u[5] = bf_round(vb.y);
  pk.u[6] = bf_round(vb.z); pk.u[7] = bf_round(vb.w);
  *reinterpret_cast<uint4*>(out + i) = pk.v;
}

// ---------------- async global->LDS 16B ----------------
DEV_INLINE void gload_lds16(const unsigned short* g, unsigned short* l) {
  __builtin_amdgcn_global_load_lds(
      (const __attribute__((address_space(1))) unsigned int*)g,
      (__attribute__((address_space(3))) unsigned int*)l,
      16, 0, 0);
}

// ---------------- fused QKV GEMM ----------------
struct QkvArgs {
  const unsigned short* W[3];
  const float* bias[3];
  unsigned short* out[3];
};
__global__ __launch_bounds__(256) void gemm_qkv(const unsigned short* __restrict__ A,
                                                QkvArgs args) {
  constexpr int K = DM;
  __shared__ unsigned short lA[128 * 32];
  __shared__ unsigned short lB[128 * 32];
  const int tid = threadIdx.x;
  const int wave = tid >> 6, lane = tid & 63;
  const int wm = wave >> 1, wn = wave & 1;
  const int g = lane >> 4, c = lane & 15;
  const int bm = blockIdx.x, bn = blockIdx.y, z = blockIdx.z;

  const unsigned short* __restrict__ W = args.W[z];
  const float* __restrict__ bias = args.bias[z];
  unsigned short* __restrict__ outp = args.out[z];

  const int srow = lane >> 2;
  const int scol = (lane & 3) * 8;

  f32x4 acc[4][4] = {};

  const unsigned short* Abase = A + (long)(bm * 128) * K;
  const unsigned short* Wbase = W + (long)(bn * 128) * K;

  for (int k0 = 0; k0 < K; k0 += 32) {
    __syncthreads();
#pragma unroll
    for (int i = 0; i < 2; ++i) {
      const int row = i * 64 + wave * 16;
      gload_lds16(Abase + (long)(row + srow) * K + k0 + scol, lA + row * 32);
      gload_lds16(Wbase + (long)(row + srow) * K + k0 + scol, lB + row * 32);
    }
    __syncthreads();

    short8 af[4], bf[4];
#pragma unroll
    for (int mi = 0; mi < 4; ++mi)
      af[mi] = *reinterpret_cast<const short8*>(&lA[(wm * 64 + mi * 16 + c) * 32 + g * 8]);
#pragma unroll
    for (int ni = 0; ni < 4; ++ni)
      bf[ni] = *reinterpret_cast<const short8*>(&lB[(wn * 64 + ni * 16 + c) * 32 + g * 8]);
#pragma unroll
    for (int mi = 0; mi < 4; ++mi)
#pragma unroll
      for (int ni = 0; ni < 4; ++ni)
        acc[mi][ni] =
            __builtin_amdgcn_mfma_f32_16x16x32_bf16(af[mi], bf[ni], acc[mi][ni], 0, 0, 0);
  }

#pragma unroll
  for (int mi = 0; mi < 4; ++mi) {
#pragma unroll
    for (int ni = 0; ni < 4; ++ni) {
      const int mg0 = bm * 128 + wm * 64 + mi * 16 + g * 4;
      const int ng = bn * 128 + wn * 64 + ni * 16 + c;
      const float bv = bias[ng];
#pragma unroll
      for (int r = 0; r < 4; ++r) {
        const int m = mg0 + r;
        float v = acc[mi][ni][r] + bv;
        if (z == 0) v *= QSCALE;
        const int b_ = m >> 11, s_ = m & 2047, h_ = ng >> 6, d_ = ng & 63;
        if (z < 2) {
          outp[((long)(b_ * NH + h_) * S_LEN + s_) * DK + d_] = bf_round(v);
        } else {
          outp[((long)(b_ * NH + h_) * DK + d_) * S_LEN + s_] = bf_round(v);
        }
      }
    }
  }
}

// ---------------- output-projection GEMM (fp32 out) ----------------
__global__ __launch_bounds__(256) void gemm_out(const unsigned short* __restrict__ A,
                                                const unsigned short* __restrict__ W,
                                                const float* __restrict__ bias,
                                                float* __restrict__ outp) {
  constexpr int K = DM, N = DM;
  __shared__ unsigned short lA[128 * 32];
  __shared__ unsigned short lB[128 * 32];
  const int tid = threadIdx.x;
  const int wave = tid >> 6, lane = tid & 63;
  const int wm = wave >> 1, wn = wave & 1;
  const int g = lane >> 4, c = lane & 15;
  const int bm = blockIdx.x, bn = blockIdx.y;

  const int srow = lane >> 2;
  const int scol = (lane & 3) * 8;

  f32x4 acc[4][4] = {};

  const unsigned short* Abase = A + (long)(bm * 128) * K;
  const unsigned short* Wbase = W + (long)(bn * 128) * K;

  for (int k0 = 0; k0 < K; k0 += 32) {
    __syncthreads();
#pragma unroll
    for (int i = 0; i < 2; ++i) {
      const int row = i * 64 + wave * 16;
      gload_lds16(Abase + (long)(row + srow) * K + k0 + scol, lA + row * 32);
      gload_lds16(Wbase + (long)(row + srow) * K + k0 + scol, lB + row * 32);
    }
    __syncthreads();

    short8 af[4], bf[4];
#pragma unroll
    for (int mi = 0; mi < 4; ++mi)
      af[mi] = *reinterpret_cast<const short8*>(&lA[(wm * 64 + mi * 16 + c) * 32 + g * 8]);
#pragma unroll
    for (int ni = 0; ni < 4; ++ni)
      bf[ni] = *reinterpret_cast<const short8*>(&lB[(wn * 64 + ni * 16 + c) * 32 + g * 8]);
#pragma unroll
    for (int mi = 0; mi < 4; ++mi)
#pragma unroll
      for (int ni = 0; ni < 4; ++ni)
        acc[mi][ni] =
            __builtin_amdgcn_mfma_f32_16x16x32_bf16(af[mi], bf[ni], acc[mi][ni], 0, 0, 0);
  }

#pragma unroll
  for (int mi = 0; mi < 4; ++mi) {
#pragma unroll
    for (int ni = 0; ni < 4; ++ni) {
      const int mg0 = bm * 128 + wm * 64 + mi * 16 + g * 4;
      const int ng = bn * 128 + wn * 64 + ni * 16 + c;
      const float bv = bias[ng];
#pragma unroll
      for (int r = 0; r < 4; ++r)
        outp[(long)(mg0 + r) * N + ng] = acc[mi][ni][r] + bv;
    }
  }
}

// ---------------- Flash attention: 2-phase LDS-staged, KV tile = 64 ----------------
// Q: [BH][S][DK] bf16 (pre-scaled QSCALE), K: [BH][S][DK] bf16, Vt: [BH][DK][S] bf16
// ctx out: [B][S][H*DK] bf16.
// Block = 4 waves, each owning 32 q-rows (128 q/block), full KV sweep (32 iters).
// Per iter: stage NEXT 64-kv K+V tile into LDS (global_load_lds, double-buffered,
// XOR-swizzled via pre-swizzled global source per m173); compute CURRENT tile
// (2 independent 32x32 S^T tiles -> combined online softmax -> PV); __syncthreads.
// Swizzle: lds byte col ^= (row&7)<<4  (T2; kills the stride-128B 32-way conflict).
__global__ __launch_bounds__(256) void attn_kernel(const unsigned short* __restrict__ Q,
                                                   const unsigned short* __restrict__ Kb,
                                                   const unsigned short* __restrict__ Vt,
                                                   unsigned short* __restrict__ ctx) {
  __shared__ unsigned short kbuf[2][64 * 64];  // [kv row][d], 128B rows, swizzled
  __shared__ unsigned short vbuf[2][64 * 64];  // [d row][kv], 128B rows, swizzled
  const int tid = threadIdx.x, wave = tid >> 6, lane = tid & 63;
  const int q = lane & 31;   // q column; also K/V LDS row selector
  const int h = lane >> 5;   // half-wave: owns k-slice h*8..h*8+7 of frags
  const int bid = blockIdx.x;
  const int swz = (bid & 7) * 128 + (bid >> 3);  // nwg=1024, 8 XCDs, bijective
  const int hd = swz >> 4, qb = swz & 15;
  const int q0 = qb * 128 + wave * 32;

  const unsigned short* Qh = Q + (long)hd * S_LEN * DK;
  const char* KhB = (const char*)(Kb + (long)hd * S_LEN * DK);
  const char* VhB = (const char*)(Vt + (long)hd * DK * S_LEN);

  // staging geometry: each gload covers 8 rows x 128B; source col pre-swizzled
  const int srow_in = lane >> 3;                           // 0..7
  const int scolb = ((lane & 7) * 16) ^ (srow_in << 4);    // swizzled source byte col

  // swizzled LDS read: 16B at (row, colbyte)
  auto ldsrd = [&](const unsigned short* buf, int row, int colbyte) -> short8 {
    return *reinterpret_cast<const short8*>(
        reinterpret_cast<const char*>(buf) + row * 128 + (colbyte ^ ((row & 7) << 4)));
  };

  auto stage = [&](int b, int kv0) {
#pragma unroll
    for (int r = 0; r < 2; ++r) {
      const int rowbase = (wave * 2 + r) * 8;          // wave-uniform
      const int row = rowbase + srow_in;
      gload_lds16((const unsigned short*)(KhB + (long)(kv0 + row) * 128 + scolb),
                  &kbuf[b][rowbase * 64]);
      gload_lds16((const unsigned short*)(VhB + (long)row * (S_LEN * 2) + kv0 * 2 + scolb),
                  &vbuf[b][rowbase * 64]);
    }
  };

  short8 qf[4];
#pragma unroll
  for (int d0 = 0; d0 < 4; ++d0)
    qf[d0] = *reinterpret_cast<const short8*>(&Qh[(long)(q0 + q) * DK + d0 * 16 + h * 8]);

  f32x16 cacc0 = {}, cacc1 = {};  // ctx^T: d-blocks [0..31], [32..63] x 32 q
  float mrun = -1e30f, lrun = 0.0f;

  stage(0, 0);
  __syncthreads();

  int cur = 0;
  for (int t = 0; t < S_LEN / 64; ++t) {
    if (t + 1 < S_LEN / 64) stage(cur ^ 1, (t + 1) * 64);  // issue-early prefetch

    const unsigned short* kb = kbuf[cur];
    const unsigned short* vb = vbuf[cur];

    // ---- QK^T: two independent S^T tiles (kv 0-31, 32-63 of this tile) ----
    short8 kfA[4], kfB[4];
#pragma unroll
    for (int d0 = 0; d0 < 4; ++d0) {
      kfA[d0] = ldsrd(kb, q, d0 * 32 + h * 16);
      kfB[d0] = ldsrd(kb, 32 + q, d0 * 32 + h * 16);
    }
    __builtin_amdgcn_s_setprio(1);
    f32x16 stA = {}, stB = {};
#pragma unroll
    for (int d0 = 0; d0 < 4; ++d0) {
      stA = __builtin_amdgcn_mfma_f32_32x32x16_bf16(kfA[d0], qf[d0], stA, 0, 0, 0);
      stB = __builtin_amdgcn_mfma_f32_32x32x16_bf16(kfB[d0], qf[d0], stB, 0, 0, 0);
    }
    __builtin_amdgcn_s_setprio(0);
    // lane reg r: q col = q, kv_local = (r&3) + 8*(r>>2) + 4*h  (+32 for tile B)

    // ---- online softmax over 32 kv (defer-max, THR=8 in log2 units) ----
    float t16[16];
#pragma unroll
    for (int r = 0; r < 16; ++r) t16[r] = fmaxf(stA[r], stB[r]);
#pragma unroll
    for (int r = 0; r < 8; ++r) t16[r] = fmaxf(t16[r], t16[r + 8]);
#pragma unroll
    for (int r = 0; r < 4; ++r) t16[r] = fmaxf(t16[r], t16[r + 4]);
    float pm = fmaxf(fmaxf(t16[0], t16[1]), fmaxf(t16[2], t16[3]));
    pm = fmaxf(pm, __shfl_xor(pm, 32));

    if (__any(pm > mrun + 8.0f)) {  // wave-uniform rescale branch
      const float mnew = fmaxf(mrun, pm);
      const float alpha = __builtin_amdgcn_exp2f(mrun - mnew);
      cacc0 *= alpha;
      cacc1 *= alpha;
      lrun *= alpha;
      mrun = mnew;
    }

#pragma unroll
    for (int r = 0; r < 16; ++r) {
      stA[r] = __builtin_amdgcn_exp2f(stA[r] - mrun);
      stB[r] = __builtin_amdgcn_exp2f(stB[r] - mrun);
    }
    float s16[16];
#pragma unroll
    for (int r = 0; r < 16; ++r) s16[r] = stA[r] + stB[r];
#pragma unroll
    for (int r = 0; r < 8; ++r) s16[r] = s16[r] + s16[r + 8];
#pragma unroll
    for (int r = 0; r < 4; ++r) s16[r] = s16[r] + s16[r + 4];
    float ls = (s16[0] + s16[1]) + (s16[2] + s16[3]);
    ls += __shfl_xor(ls, 32);
    lrun += ls;

    // ---- pack P -> bf16 pairs, per tile ----
    unsigned pAA[4], pAB[4], pBA[4], pBB[4];
#pragma unroll
    for (int rq = 0; rq < 4; ++rq) {
      asm("v_cvt_pk_bf16_f32 %0, %1, %2" : "=v"(pAA[rq]) : "v"(stA[4 * rq]), "v"(stA[4 * rq + 1]));
      asm("v_cvt_pk_bf16_f32 %0, %1, %2" : "=v"(pAB[rq]) : "v"(stA[4 * rq + 2]), "v"(stA[4 * rq + 3]));
      asm("v_cvt_pk_bf16_f32 %0, %1, %2" : "=v"(pBA[rq]) : "v"(stB[4 * rq]), "v"(stB[4 * rq + 1]));
      asm("v_cvt_pk_bf16_f32 %0, %1, %2" : "=v"(pBB[rq]) : "v"(stB[4 * rq + 2]), "v"(stB[4 * rq + 3]));
    }

    // ---- PV: ctx^T += V^T[d][kv] @ P^T[kv][q], four 16-kv steps ----
    auto pvstep = [&](unsigned a0, unsigned b0, unsigned a1, unsigned b1, int colbyte) {
      unsigned sA = h ? a0 : a1;
      unsigned sB = h ? b0 : b1;
      unsigned rA = (unsigned)__shfl_xor((int)sA, 32);
      unsigned rB = (unsigned)__shfl_xor((int)sB, 32);
      union { unsigned w[4]; short8 v; } pf;
      pf.w[0] = h ? rA : a0;
      pf.w[1] = h ? rB : b0;
      pf.w[2] = h ? a1 : rA;
      pf.w[3] = h ? b1 : rB;
      short8 vf0 = ldsrd(vb, q, colbyte + h * 16);
      short8 vf1 = ldsrd(vb, 32 + q, colbyte + h * 16);
      __builtin_amdgcn_s_setprio(1);
      cacc0 = __builtin_amdgcn_mfma_f32_32x32x16_bf16(vf0, pf.v, cacc0, 0, 0, 0);
      cacc1 = __builtin_amdgcn_mfma_f32_32x32x16_bf16(vf1, pf.v, cacc1, 0, 0, 0);
      __builtin_amdgcn_s_setprio(0);
    };
    pvstep(pAA[0], pAB[0], pAA[1], pAB[1], 0);
    pvstep(pAA[2], pAB[2], pAA[3], pAB[3], 32);
    pvstep(pBA[0], pBB[0], pBA[1], pBB[1], 64);
    pvstep(pBA[2], pBB[2], pBA[3], pBB[3], 96);

    __syncthreads();  // drains stage loads; protects both buffers
    cur ^= 1;
  }

  // ---- epilogue: ctx^T[d][q] -> ctx[b][s=q0+q][h_*64 + d], d = db*32 + 8*rq + 4*h + rr ----
  const float inv = 1.0f / lrun;
  const int b_ = hd >> 4, h_ = hd & 15;
  const long row = ((long)b_ * S_LEN + q0 + q) * DM + h_ * DK;
#pragma unroll
  for (int rq = 0; rq < 4; ++rq) {
    ushort4 w0, w1;
    w0.x = bf_round(cacc0[4 * rq + 0] * inv);
    w0.y = bf_round(cacc0[4 * rq + 1] * inv);
    w0.z = bf_round(cacc0[4 * rq + 2] * inv);
    w0.w = bf_round(cacc0[4 * rq + 3] * inv);
    w1.x = bf_round(cacc1[4 * rq + 0] * inv);
    w1.y = bf_round(cacc1[4 * rq + 1] * inv);
    w1.z = bf_round(cacc1[4 * rq + 2] * inv);
    w1.w = bf_round(cacc1[4 * rq + 3] * inv);
    *reinterpret_cast<ushort4*>(&ctx[row + 8 * rq + 4 * h]) = w0;
    *reinterpret_cast<ushort4*>(&ctx[row + 32 + 8 * rq + 4 * h]) = w1;
  }
}

extern "C" void kernel_launch(void* const* d_in, const int* in_sizes, int n_in,
                              void* d_out, int out_size, void* d_ws, size_t ws_size,
                              hipStream_t stream) {
  const float* X  = (const float*)d_in[0];
  const float* Wq = (const float*)d_in[1];
  const float* bq = (const float*)d_in[2];
  const float* Wk = (const float*)d_in[3];
  const float* bk = (const float*)d_in[4];
  const float* Wv = (const float*)d_in[5];
  const float* bv = (const float*)d_in[6];
  const float* Wo = (const float*)d_in[7];
  const float* bo = (const float*)d_in[8];

  char* ws = (char*)d_ws;
  const long MB = 1l << 20;
  unsigned short* Xbf = (unsigned short*)(ws + 0 * MB);   // 16 MB
  unsigned short* Ctx = Xbf;                              // alias: X dead after V GEMM
  unsigned short* Wqb = (unsigned short*)(ws + 16 * MB);  // 2 MB each
  unsigned short* Wkb = (unsigned short*)(ws + 18 * MB);
  unsigned short* Wvb = (unsigned short*)(ws + 20 * MB);
  unsigned short* Wob = (unsigned short*)(ws + 22 * MB);
  unsigned short* Qb  = (unsigned short*)(ws + 24 * MB);  // 16 MB
  unsigned short* Kbf = (unsigned short*)(ws + 40 * MB);  // 16 MB
  unsigned short* Vtb = (unsigned short*)(ws + 56 * MB);  // 16 MB, ends at 72 MB

  CvtArgs ca;
  ca.in[0] = X;  ca.out[0] = Xbf;
  ca.in[1] = Wq; ca.out[1] = Wqb;
  ca.in[2] = Wk; ca.out[2] = Wkb;
  ca.in[3] = Wv; ca.out[3] = Wvb;
  ca.in[4] = Wo; ca.out[4] = Wob;
  cvt_all<<<4096 + 4 * 512, 256, 0, stream>>>(ca);

  QkvArgs qa;
  qa.W[0] = Wqb; qa.bias[0] = bq; qa.out[0] = Qb;
  qa.W[1] = Wkb; qa.bias[1] = bk; qa.out[1] = Kbf;
  qa.W[2] = Wvb; qa.bias[2] = bv; qa.out[2] = Vtb;
  gemm_qkv<<<dim3(M_TOT / 128, DM / 128, 3), 256, 0, stream>>>(Xbf, qa);

  attn_kernel<<<dim3(1024), 256, 0, stream>>>(Qb, Kbf, Vtb, Ctx);

  gemm_out<<<dim3(M_TOT / 128, DM / 128), 256, 0, stream>>>(Ctx, Wob, bo, (float*)d_out);
}

// Round 7
// 227.718 us; speedup vs baseline: 1.5151x; 1.0180x over previous
//
#include <hip/hip_runtime.h>
#include <hip/hip_bf16.h>
#include <stdint.h>

#define DEV_INLINE __device__ __forceinline__

typedef __attribute__((ext_vector_type(4))) float f32x4;
typedef __attribute__((ext_vector_type(16))) float f32x16;
typedef __attribute__((ext_vector_type(8))) short short8;

static constexpr int S_LEN = 2048;
static constexpr int DM = 1024;
static constexpr int NH = 16;
static constexpr int DK = 64;
static constexpr int BATCH = 4;
static constexpr int M_TOT = BATCH * S_LEN;  // 8192

// Q pre-scale: (1/sqrt(64)) * log2(e) so softmax runs in exp2 domain.
#define QSCALE 0.18033688011112042f

DEV_INLINE unsigned short bf_round(float x) {
  unsigned u = __builtin_bit_cast(unsigned, x);
  u += 0x7fffu + ((u >> 16) & 1u);
  return (unsigned short)(u >> 16);
}

// ---------------- fp32 -> bf16 convert, all 5 tensors in one dispatch ----------------
struct CvtArgs {
  const float* in[5];
  unsigned short* out[5];
};
__global__ __launch_bounds__(256) void cvt_all(CvtArgs a) {
  int bid = blockIdx.x;
  int which, base;
  if (bid < 4096) { which = 0; base = bid; }
  else { int r = bid - 4096; which = 1 + (r >> 9); base = r & 511; }
  const float* __restrict__ in = a.in[which];
  unsigned short* __restrict__ out = a.out[which];
  long i = ((long)base * 256 + threadIdx.x) * 8;
  float4 va = *reinterpret_cast<const float4*>(in + i);
  float4 vb = *reinterpret_cast<const float4*>(in + i + 4);
  union { unsigned short u[8]; uint4 v; } pk;
  pk.u[0] = bf_round(va.x); pk.u[1] = bf_round(va.y);
  pk.u[2] = bf_round(va.z); pk.u[3] = bf_round(va.w);
  pk.u[4] = bf_round(vb.x); pk.u[5] = bf_round(vb.y);
  pk.u[6] = bf_round(vb.z); pk.u[7] = bf_round(vb.w);
  *reinterpret_cast<uint4*>(out + i) = pk.v;
}

// ---------------- async global->LDS 16B ----------------
DEV_INLINE void gload_lds16(const unsigned short* g, unsigned short* l) {
  __builtin_amdgcn_global_load_lds(
      (const __attribute__((address_space(1))) unsigned int*)g,
      (__attribute__((address_space(3))) unsigned int*)l,
      16, 0, 0);
}

// ---------------- fused QKV GEMM ----------------
struct QkvArgs {
  const unsigned short* W[3];
  const float* bias[3];
  unsigned short* out[3];
};
__global__ __launch_bounds__(256) void gemm_qkv(const unsigned short* __restrict__ A,
                                                QkvArgs args) {
  constexpr int K = DM;
  __shared__ unsigned short lA[128 * 32];
  __shared__ unsigned short lB[128 * 32];
  const int tid = threadIdx.x;
  const int wave = tid >> 6, lane = tid & 63;
  const int wm = wave >> 1, wn = wave & 1;
  const int g = lane >> 4, c = lane & 15;
  const int bm = blockIdx.x, bn = blockIdx.y, z = blockIdx.z;

  const unsigned short* __restrict__ W = args.W[z];
  const float* __restrict__ bias = args.bias[z];
  unsigned short* __restrict__ outp = args.out[z];

  const int srow = lane >> 2;
  const int scol = (lane & 3) * 8;

  f32x4 acc[4][4] = {};

  const unsigned short* Abase = A + (long)(bm * 128) * K;
  const unsigned short* Wbase = W + (long)(bn * 128) * K;

  for (int k0 = 0; k0 < K; k0 += 32) {
    __syncthreads();
#pragma unroll
    for (int i = 0; i < 2; ++i) {
      const int row = i * 64 + wave * 16;
      gload_lds16(Abase + (long)(row + srow) * K + k0 + scol, lA + row * 32);
      gload_lds16(Wbase + (long)(row + srow) * K + k0 + scol, lB + row * 32);
    }
    __syncthreads();

    short8 af[4], bf[4];
#pragma unroll
    for (int mi = 0; mi < 4; ++mi)
      af[mi] = *reinterpret_cast<const short8*>(&lA[(wm * 64 + mi * 16 + c) * 32 + g * 8]);
#pragma unroll
    for (int ni = 0; ni < 4; ++ni)
      bf[ni] = *reinterpret_cast<const short8*>(&lB[(wn * 64 + ni * 16 + c) * 32 + g * 8]);
#pragma unroll
    for (int mi = 0; mi < 4; ++mi)
#pragma unroll
      for (int ni = 0; ni < 4; ++ni)
        acc[mi][ni] =
            __builtin_amdgcn_mfma_f32_16x16x32_bf16(af[mi], bf[ni], acc[mi][ni], 0, 0, 0);
  }

#pragma unroll
  for (int mi = 0; mi < 4; ++mi) {
#pragma unroll
    for (int ni = 0; ni < 4; ++ni) {
      const int mg0 = bm * 128 + wm * 64 + mi * 16 + g * 4;
      const int ng = bn * 128 + wn * 64 + ni * 16 + c;
      const float bv = bias[ng];
#pragma unroll
      for (int r = 0; r < 4; ++r) {
        const int m = mg0 + r;
        float v = acc[mi][ni][r] + bv;
        if (z == 0) v *= QSCALE;
        const int b_ = m >> 11, s_ = m & 2047, h_ = ng >> 6, d_ = ng & 63;
        if (z < 2) {
          outp[((long)(b_ * NH + h_) * S_LEN + s_) * DK + d_] = bf_round(v);
        } else {
          outp[((long)(b_ * NH + h_) * DK + d_) * S_LEN + s_] = bf_round(v);
        }
      }
    }
  }
}

// ---------------- output-projection GEMM (fp32 out) ----------------
__global__ __launch_bounds__(256) void gemm_out(const unsigned short* __restrict__ A,
                                                const unsigned short* __restrict__ W,
                                                const float* __restrict__ bias,
                                                float* __restrict__ outp) {
  constexpr int K = DM, N = DM;
  __shared__ unsigned short lA[128 * 32];
  __shared__ unsigned short lB[128 * 32];
  const int tid = threadIdx.x;
  const int wave = tid >> 6, lane = tid & 63;
  const int wm = wave >> 1, wn = wave & 1;
  const int g = lane >> 4, c = lane & 15;
  const int bm = blockIdx.x, bn = blockIdx.y;

  const int srow = lane >> 2;
  const int scol = (lane & 3) * 8;

  f32x4 acc[4][4] = {};

  const unsigned short* Abase = A + (long)(bm * 128) * K;
  const unsigned short* Wbase = W + (long)(bn * 128) * K;

  for (int k0 = 0; k0 < K; k0 += 32) {
    __syncthreads();
#pragma unroll
    for (int i = 0; i < 2; ++i) {
      const int row = i * 64 + wave * 16;
      gload_lds16(Abase + (long)(row + srow) * K + k0 + scol, lA + row * 32);
      gload_lds16(Wbase + (long)(row + srow) * K + k0 + scol, lB + row * 32);
    }
    __syncthreads();

    short8 af[4], bf[4];
#pragma unroll
    for (int mi = 0; mi < 4; ++mi)
      af[mi] = *reinterpret_cast<const short8*>(&lA[(wm * 64 + mi * 16 + c) * 32 + g * 8]);
#pragma unroll
    for (int ni = 0; ni < 4; ++ni)
      bf[ni] = *reinterpret_cast<const short8*>(&lB[(wn * 64 + ni * 16 + c) * 32 + g * 8]);
#pragma unroll
    for (int mi = 0; mi < 4; ++mi)
#pragma unroll
      for (int ni = 0; ni < 4; ++ni)
        acc[mi][ni] =
            __builtin_amdgcn_mfma_f32_16x16x32_bf16(af[mi], bf[ni], acc[mi][ni], 0, 0, 0);
  }

#pragma unroll
  for (int mi = 0; mi < 4; ++mi) {
#pragma unroll
    for (int ni = 0; ni < 4; ++ni) {
      const int mg0 = bm * 128 + wm * 64 + mi * 16 + g * 4;
      const int ng = bn * 128 + wn * 64 + ni * 16 + c;
      const float bv = bias[ng];
#pragma unroll
      for (int r = 0; r < 4; ++r)
        outp[(long)(mg0 + r) * N + ng] = acc[mi][ni][r] + bv;
    }
  }
}

// ---------------- Flash attention: 2-phase LDS-staged, KV tile = 64 ----------------
// Q: [BH][S][DK] bf16 (pre-scaled QSCALE), K: [BH][S][DK] bf16, Vt: [BH][DK][S] bf16
// ctx out: [B][S][H*DK] bf16.
// Block = 4 waves x 32 q-rows, full KV sweep (32 iters), double-buffered LDS tiles.
// Round-7 chain cuts: batched PV shuffles + V-reads (latencies overlap instead of
// 4x serial), branch-only defer check (no cross-lane shfl on common path),
// deferred lane-half l-sum (one shfl at end instead of per-iter).
__global__ __launch_bounds__(256) void attn_kernel(const unsigned short* __restrict__ Q,
                                                   const unsigned short* __restrict__ Kb,
                                                   const unsigned short* __restrict__ Vt,
                                                   unsigned short* __restrict__ ctx) {
  __shared__ unsigned short kbuf[2][64 * 64];  // [kv row][d], 128B rows, swizzled
  __shared__ unsigned short vbuf[2][64 * 64];  // [d row][kv], 128B rows, swizzled
  const int tid = threadIdx.x, wave = tid >> 6, lane = tid & 63;
  const int q = lane & 31;   // q column; also K/V LDS row selector
  const int h = lane >> 5;   // half-wave: owns k-slice h*8..h*8+7 of frags
  const int bid = blockIdx.x;
  const int swz = (bid & 7) * 128 + (bid >> 3);  // nwg=1024, 8 XCDs, bijective
  const int hd = swz >> 4, qb = swz & 15;
  const int q0 = qb * 128 + wave * 32;

  const unsigned short* Qh = Q + (long)hd * S_LEN * DK;
  const char* KhB = (const char*)(Kb + (long)hd * S_LEN * DK);
  const char* VhB = (const char*)(Vt + (long)hd * DK * S_LEN);

  // staging geometry: each gload covers 8 rows x 128B; source col pre-swizzled
  const int srow_in = lane >> 3;                           // 0..7
  const int scolb = ((lane & 7) * 16) ^ (srow_in << 4);    // swizzled source byte col

  // swizzled LDS read: 16B at (row, colbyte)
  auto ldsrd = [&](const unsigned short* buf, int row, int colbyte) -> short8 {
    return *reinterpret_cast<const short8*>(
        reinterpret_cast<const char*>(buf) + row * 128 + (colbyte ^ ((row & 7) << 4)));
  };

  auto stage = [&](int b, int kv0) {
#pragma unroll
    for (int r = 0; r < 2; ++r) {
      const int rowbase = (wave * 2 + r) * 8;          // wave-uniform
      const int row = rowbase + srow_in;
      gload_lds16((const unsigned short*)(KhB + (long)(kv0 + row) * 128 + scolb),
                  &kbuf[b][rowbase * 64]);
      gload_lds16((const unsigned short*)(VhB + (long)row * (S_LEN * 2) + kv0 * 2 + scolb),
                  &vbuf[b][rowbase * 64]);
    }
  };

  short8 qf[4];
#pragma unroll
  for (int d0 = 0; d0 < 4; ++d0)
    qf[d0] = *reinterpret_cast<const short8*>(&Qh[(long)(q0 + q) * DK + d0 * 16 + h * 8]);

  f32x16 cacc0 = {}, cacc1 = {};  // ctx^T: d-blocks [0..31], [32..63] x 32 q
  float mrun = -1e30f, lrun = 0.0f;  // lrun = this lane-half's partial sum

  stage(0, 0);
  __syncthreads();

  int cur = 0;
  for (int t = 0; t < S_LEN / 64; ++t) {
    if (t + 1 < S_LEN / 64) stage(cur ^ 1, (t + 1) * 64);  // issue-early prefetch

    const unsigned short* kb = kbuf[cur];
    const unsigned short* vb = vbuf[cur];

    // ---- QK^T: two independent S^T tiles (kv 0-31, 32-63 of this tile) ----
    short8 kfA[4], kfB[4];
#pragma unroll
    for (int d0 = 0; d0 < 4; ++d0) {
      kfA[d0] = ldsrd(kb, q, d0 * 32 + h * 16);
      kfB[d0] = ldsrd(kb, 32 + q, d0 * 32 + h * 16);
    }
    __builtin_amdgcn_s_setprio(1);
    f32x16 stA = {}, stB = {};
#pragma unroll
    for (int d0 = 0; d0 < 4; ++d0) {
      stA = __builtin_amdgcn_mfma_f32_32x32x16_bf16(kfA[d0], qf[d0], stA, 0, 0, 0);
      stB = __builtin_amdgcn_mfma_f32_32x32x16_bf16(kfB[d0], qf[d0], stB, 0, 0, 0);
    }
    __builtin_amdgcn_s_setprio(0);
    // lane reg r: q col = q, kv_local = (r&3) + 8*(r>>2) + 4*h  (+32 for tile B)

    // ---- online softmax (defer-max; common path has NO cross-lane op) ----
    float t16[16];
#pragma unroll
    for (int r = 0; r < 16; ++r) t16[r] = fmaxf(stA[r], stB[r]);
#pragma unroll
    for (int r = 0; r < 8; ++r) t16[r] = fmaxf(t16[r], t16[r + 8]);
#pragma unroll
    for (int r = 0; r < 4; ++r) t16[r] = fmaxf(t16[r], t16[r + 4]);
    const float pml = fmaxf(fmaxf(t16[0], t16[1]), fmaxf(t16[2], t16[3]));

    if (__any(pml > mrun + 8.0f)) {  // rare; shfl only inside the branch
      const float pm = fmaxf(pml, __shfl_xor(pml, 32));
      const float mnew = fmaxf(mrun, pm);
      const float alpha = __builtin_amdgcn_exp2f(mrun - mnew);
      cacc0 *= alpha;
      cacc1 *= alpha;
      lrun *= alpha;
      mrun = mnew;  // stays pair-uniform: pm is pair-reduced
    }

#pragma unroll
    for (int r = 0; r < 16; ++r) {
      stA[r] = __builtin_amdgcn_exp2f(stA[r] - mrun);
      stB[r] = __builtin_amdgcn_exp2f(stB[r] - mrun);
    }
    float s16[16];
#pragma unroll
    for (int r = 0; r < 16; ++r) s16[r] = stA[r] + stB[r];
#pragma unroll
    for (int r = 0; r < 8; ++r) s16[r] = s16[r] + s16[r + 8];
#pragma unroll
    for (int r = 0; r < 4; ++r) s16[r] = s16[r] + s16[r + 4];
    lrun += (s16[0] + s16[1]) + (s16[2] + s16[3]);  // lane-half partial; no shfl

    // ---- pack P -> bf16 pairs, per tile ----
    unsigned pAA[4], pAB[4], pBA[4], pBB[4];
#pragma unroll
    for (int rq = 0; rq < 4; ++rq) {
      asm("v_cvt_pk_bf16_f32 %0, %1, %2" : "=v"(pAA[rq]) : "v"(stA[4 * rq]), "v"(stA[4 * rq + 1]));
      asm("v_cvt_pk_bf16_f32 %0, %1, %2" : "=v"(pAB[rq]) : "v"(stA[4 * rq + 2]), "v"(stA[4 * rq + 3]));
      asm("v_cvt_pk_bf16_f32 %0, %1, %2" : "=v"(pBA[rq]) : "v"(stB[4 * rq]), "v"(stB[4 * rq + 1]));
      asm("v_cvt_pk_bf16_f32 %0, %1, %2" : "=v"(pBB[rq]) : "v"(stB[4 * rq + 2]), "v"(stB[4 * rq + 3]));
    }

    // ---- PV: batch-issue all 8 shuffles, then all 8 V-reads (latencies overlap),
    //      then 4x {select + 2 MFMA}. step s: tile X=(s<2?A:B), u=s&1, colbyte=32*s.
    unsigned rA[4], rB[4];
#pragma unroll
    for (int s = 0; s < 4; ++s) {
      const unsigned a0 = (s < 2 ? pAA : pBA)[2 * (s & 1)];
      const unsigned a1 = (s < 2 ? pAA : pBA)[2 * (s & 1) + 1];
      const unsigned b0 = (s < 2 ? pAB : pBB)[2 * (s & 1)];
      const unsigned b1 = (s < 2 ? pAB : pBB)[2 * (s & 1) + 1];
      rA[s] = (unsigned)__shfl_xor((int)(h ? a0 : a1), 32);
      rB[s] = (unsigned)__shfl_xor((int)(h ? b0 : b1), 32);
    }
    short8 vf0[4], vf1[4];
#pragma unroll
    for (int s = 0; s < 4; ++s) {
      vf0[s] = ldsrd(vb, q, s * 32 + h * 16);
      vf1[s] = ldsrd(vb, 32 + q, s * 32 + h * 16);
    }
    __builtin_amdgcn_s_setprio(1);
#pragma unroll
    for (int s = 0; s < 4; ++s) {
      const unsigned a0 = (s < 2 ? pAA : pBA)[2 * (s & 1)];
      const unsigned a1 = (s < 2 ? pAA : pBA)[2 * (s & 1) + 1];
      const unsigned b0 = (s < 2 ? pAB : pBB)[2 * (s & 1)];
      const unsigned b1 = (s < 2 ? pAB : pBB)[2 * (s & 1) + 1];
      union { unsigned w[4]; short8 v; } pf;
      pf.w[0] = h ? rA[s] : a0;
      pf.w[1] = h ? rB[s] : b0;
      pf.w[2] = h ? a1 : rA[s];
      pf.w[3] = h ? b1 : rB[s];
      cacc0 = __builtin_amdgcn_mfma_f32_32x32x16_bf16(vf0[s], pf.v, cacc0, 0, 0, 0);
      cacc1 = __builtin_amdgcn_mfma_f32_32x32x16_bf16(vf1[s], pf.v, cacc1, 0, 0, 0);
    }
    __builtin_amdgcn_s_setprio(0);

    __syncthreads();  // drains stage loads; protects both buffers
    cur ^= 1;
  }

  // ---- combine lane-half l-sums (single deferred shfl), then epilogue ----
  lrun += __shfl_xor(lrun, 32);
  const float inv = 1.0f / lrun;
  const int b_ = hd >> 4, h_ = hd & 15;
  const long row = ((long)b_ * S_LEN + q0 + q) * DM + h_ * DK;
#pragma unroll
  for (int rq = 0; rq < 4; ++rq) {
    ushort4 w0, w1;
    w0.x = bf_round(cacc0[4 * rq + 0] * inv);
    w0.y = bf_round(cacc0[4 * rq + 1] * inv);
    w0.z = bf_round(cacc0[4 * rq + 2] * inv);
    w0.w = bf_round(cacc0[4 * rq + 3] * inv);
    w1.x = bf_round(cacc1[4 * rq + 0] * inv);
    w1.y = bf_round(cacc1[4 * rq + 1] * inv);
    w1.z = bf_round(cacc1[4 * rq + 2] * inv);
    w1.w = bf_round(cacc1[4 * rq + 3] * inv);
    *reinterpret_cast<ushort4*>(&ctx[row + 8 * rq + 4 * h]) = w0;
    *reinterpret_cast<ushort4*>(&ctx[row + 32 + 8 * rq + 4 * h]) = w1;
  }
}

extern "C" void kernel_launch(void* const* d_in, const int* in_sizes, int n_in,
                              void* d_out, int out_size, void* d_ws, size_t ws_size,
                              hipStream_t stream) {
  const float* X  = (const float*)d_in[0];
  const float* Wq = (const float*)d_in[1];
  const float* bq = (const float*)d_in[2];
  const float* Wk = (const float*)d_in[3];
  const float* bk = (const float*)d_in[4];
  const float* Wv = (const float*)d_in[5];
  const float* bv = (const float*)d_in[6];
  const float* Wo = (const float*)d_in[7];
  const float* bo = (const float*)d_in[8];

  char* ws = (char*)d_ws;
  const long MB = 1l << 20;
  unsigned short* Xbf = (unsigned short*)(ws + 0 * MB);   // 16 MB
  unsigned short* Ctx = Xbf;                              // alias: X dead after V GEMM
  unsigned short* Wqb = (unsigned short*)(ws + 16 * MB);  // 2 MB each
  unsigned short* Wkb = (unsigned short*)(ws + 18 * MB);
  unsigned short* Wvb = (unsigned short*)(ws + 20 * MB);
  unsigned short* Wob = (unsigned short*)(ws + 22 * MB);
  unsigned short* Qb  = (unsigned short*)(ws + 24 * MB);  // 16 MB
  unsigned short* Kbf = (unsigned short*)(ws + 40 * MB);  // 16 MB
  unsigned short* Vtb = (unsigned short*)(ws + 56 * MB);  // 16 MB, ends at 72 MB

  CvtArgs ca;
  ca.in[0] = X;  ca.out[0] = Xbf;
  ca.in[1] = Wq; ca.out[1] = Wqb;
  ca.in[2] = Wk; ca.out[2] = Wkb;
  ca.in[3] = Wv; ca.out[3] = Wvb;
  ca.in[4] = Wo; ca.out[4] = Wob;
  cvt_all<<<4096 + 4 * 512, 256, 0, stream>>>(ca);

  QkvArgs qa;
  qa.W[0] = Wqb; qa.bias[0] = bq; qa.out[0] = Qb;
  qa.W[1] = Wkb; qa.bias[1] = bk; qa.out[1] = Kbf;
  qa.W[2] = Wvb; qa.bias[2] = bv; qa.out[2] = Vtb;
  gemm_qkv<<<dim3(M_TOT / 128, DM / 128, 3), 256, 0, stream>>>(Xbf, qa);

  attn_kernel<<<dim3(1024), 256, 0, stream>>>(Qb, Kbf, Vtb, Ctx);

  gemm_out<<<dim3(M_TOT / 128, DM / 128), 256, 0, stream>>>(Ctx, Wob, bo, (float*)d_out);
}